// Round 1
// baseline (846.795 us; speedup 1.0000x reference)
//
#include <hip/hip_runtime.h>
#include <hip/hip_bf16.h>
#include <math.h>

// Grok1 MoE: T=2048 tokens, H=1024, I=4096, E=8, top-2, softcap=30.
// Sparse (top-2) formulation: 103 GFLOP bf16 MFMA instead of 412 GFLOP fp32.

#define NTOK 2048
#define HDIM 1024
#define IDIM 4096
#define NEXP 8
#define SOFTCAP 30.0f

typedef __bf16 bf16;
typedef __bf16 bf16x8 __attribute__((ext_vector_type(8)));
typedef float f32x4 __attribute__((ext_vector_type(4)));

#define BM 128
#define BN 128
#define BK 32
#define APAD 40   // padded LDS row (bf16 elems): 80 B, breaks pow2 bank stride, keeps 16B align

__device__ inline float gelu_exact(float x) {
    return 0.5f * x * (1.0f + erff(x * 0.70710678118654752f));
}

__device__ inline bf16x8 cvt8(f32x4 a, f32x4 b) {
    bf16x8 r;
    r[0] = (bf16)a[0]; r[1] = (bf16)a[1]; r[2] = (bf16)a[2]; r[3] = (bf16)a[3];
    r[4] = (bf16)b[0]; r[5] = (bf16)b[1]; r[6] = (bf16)b[2]; r[7] = (bf16)b[3];
    return r;
}

// ---------------- Router: logits -> softcap -> top2 -> pairwise-sigmoid weights ----------
// One wave per token. Also converts x (fp32) -> xb (bf16).
__global__ __launch_bounds__(256) void router_kernel(
    const float* __restrict__ x, const float* __restrict__ wg,
    int* __restrict__ ctrl, int* __restrict__ route_ids, float* __restrict__ route_w,
    bf16* __restrict__ xb)
{
    int wave = threadIdx.x >> 6;
    int lane = threadIdx.x & 63;
    int t = blockIdx.x * 4 + wave;
    if (t >= NTOK) return;

    const float* xr = x + (size_t)t * HDIM;
    float xv[16];
    #pragma unroll
    for (int j = 0; j < 16; ++j) xv[j] = xr[lane + 64 * j];
    #pragma unroll
    for (int j = 0; j < 16; ++j) xb[(size_t)t * HDIM + lane + 64 * j] = (bf16)xv[j];

    float l[NEXP];
    #pragma unroll
    for (int e = 0; e < NEXP; ++e) {
        const float* wr = wg + e * HDIM;
        float p = 0.f;
        #pragma unroll
        for (int j = 0; j < 16; ++j) p += xv[j] * wr[lane + 64 * j];
        #pragma unroll
        for (int off = 32; off > 0; off >>= 1) p += __shfl_xor(p, off);
        l[e] = SOFTCAP * tanhf(p * (1.0f / SOFTCAP));
    }
    // top-2 (strict > keeps lowest index on ties, matching lax.top_k)
    int e0 = 0; float v0 = l[0];
    #pragma unroll
    for (int e = 1; e < NEXP; ++e) if (l[e] > v0) { v0 = l[e]; e0 = e; }
    int e1 = (e0 == 0) ? 1 : 0; float v1 = l[e1];
    #pragma unroll
    for (int e = 0; e < NEXP; ++e) if (e != e0 && l[e] > v1) { v1 = l[e]; e1 = e; }
    // renormalized top-2 softmax weights: Z cancels -> pairwise sigmoid
    float w0 = 1.0f / (1.0f + expf(v1 - v0));

    if (lane == 0) {
        route_ids[2 * t] = e0; route_ids[2 * t + 1] = e1;
        route_w[2 * t] = w0;   route_w[2 * t + 1] = 1.0f - w0;
        atomicAdd(&ctrl[e0], 1);
        atomicAdd(&ctrl[e1], 1);
    }
}

// ctrl layout: [0..7]=counts, [8..15]=cursor, [16..24]=offsets (exclusive prefix)
__global__ void offsets_kernel(int* __restrict__ ctrl) {
    if (threadIdx.x == 0) {
        int acc = 0;
        for (int e = 0; e < NEXP; ++e) {
            ctrl[16 + e] = acc;
            acc += ctrl[e];
            ctrl[8 + e] = 0;
        }
        ctrl[16 + NEXP] = acc;
    }
}

__global__ __launch_bounds__(256) void scatter_kernel(
    const int* __restrict__ route_ids, const float* __restrict__ route_w,
    int* __restrict__ ctrl, int* __restrict__ pair_token, float* __restrict__ pair_w,
    int* __restrict__ token_slot)
{
    int t = blockIdx.x * 256 + threadIdx.x;
    if (t >= NTOK) return;
    #pragma unroll
    for (int k = 0; k < 2; ++k) {
        int e = route_ids[2 * t + k];
        int slot = atomicAdd(&ctrl[8 + e], 1);
        int pos = ctrl[16 + e] + slot;
        pair_token[pos] = t;
        pair_w[pos] = route_w[2 * t + k];
        token_slot[2 * t + k] = pos;
    }
}

// ---------------- GEMM1: h1 = Xg @ w1^T, h3 = Xg @ w3^T, act = gelu(h1)*h3 (bf16) -------
// grid (ntile=IDIM/BN, mtile_max=16, expert). Both operands K-contiguous (NT gemm).
__global__ __launch_bounds__(256, 2) void gemm1_kernel(
    const bf16* __restrict__ xb, const float* __restrict__ w1, const float* __restrict__ w3,
    const int* __restrict__ ctrl, const int* __restrict__ pair_token,
    bf16* __restrict__ act)
{
    int e = blockIdx.z;
    int count = ctrl[e];
    int mtile = blockIdx.y;
    if (mtile * BM >= count) return;
    int off = ctrl[16 + e];
    int ntile = blockIdx.x;

    __shared__ bf16 As[BM][APAD];
    __shared__ bf16 B1s[BM][APAD];
    __shared__ bf16 B3s[BM][APAD];

    int tid = threadIdx.x;
    int lane = tid & 63, wave = tid >> 6;
    int wm = wave >> 1, wn = wave & 1;

    int sr = tid >> 1;            // staging row 0..127
    int sc = (tid & 1) * 16;      // staging col 0 or 16

    int arow = mtile * BM + sr;
    int tok = (arow < count) ? pair_token[off + arow] : 0;
    const bf16* aptr = xb + (size_t)tok * HDIM + sc;
    const float* b1p = w1 + (size_t)e * IDIM * HDIM + (size_t)(ntile * BN + sr) * HDIM + sc;
    const float* b3p = w3 + (size_t)e * IDIM * HDIM + (size_t)(ntile * BN + sr) * HDIM + sc;

    f32x4 acc1[4][4] = {};
    f32x4 acc3[4][4] = {};

    for (int k0 = 0; k0 < HDIM; k0 += BK) {
        __syncthreads();
        // A: 16 bf16 (already bf16)
        *(uint4*)&As[sr][sc]     = *(const uint4*)(aptr + k0);
        *(uint4*)&As[sr][sc + 8] = *(const uint4*)(aptr + k0 + 8);
        // B: 16 fp32 each of w1/w3, convert to bf16 in regs
        f32x4 a0 = *(const f32x4*)(b1p + k0);
        f32x4 a1 = *(const f32x4*)(b1p + k0 + 4);
        f32x4 a2 = *(const f32x4*)(b1p + k0 + 8);
        f32x4 a3 = *(const f32x4*)(b1p + k0 + 12);
        *(bf16x8*)&B1s[sr][sc]     = cvt8(a0, a1);
        *(bf16x8*)&B1s[sr][sc + 8] = cvt8(a2, a3);
        f32x4 c0 = *(const f32x4*)(b3p + k0);
        f32x4 c1 = *(const f32x4*)(b3p + k0 + 4);
        f32x4 c2 = *(const f32x4*)(b3p + k0 + 8);
        f32x4 c3 = *(const f32x4*)(b3p + k0 + 12);
        *(bf16x8*)&B3s[sr][sc]     = cvt8(c0, c1);
        *(bf16x8*)&B3s[sr][sc + 8] = cvt8(c2, c3);
        __syncthreads();

        bf16x8 af[4];
        #pragma unroll
        for (int mi = 0; mi < 4; ++mi)
            af[mi] = *(const bf16x8*)&As[wm * 64 + mi * 16 + (lane & 15)][(lane >> 4) * 8];
        #pragma unroll
        for (int ni = 0; ni < 4; ++ni) {
            bf16x8 b1f = *(const bf16x8*)&B1s[wn * 64 + ni * 16 + (lane & 15)][(lane >> 4) * 8];
            bf16x8 b3f = *(const bf16x8*)&B3s[wn * 64 + ni * 16 + (lane & 15)][(lane >> 4) * 8];
            #pragma unroll
            for (int mi = 0; mi < 4; ++mi) {
                acc1[mi][ni] = __builtin_amdgcn_mfma_f32_16x16x32_bf16(af[mi], b1f, acc1[mi][ni], 0, 0, 0);
                acc3[mi][ni] = __builtin_amdgcn_mfma_f32_16x16x32_bf16(af[mi], b3f, acc3[mi][ni], 0, 0, 0);
            }
        }
    }

    // epilogue: act = gelu(h1)*h3 -> bf16. C/D layout: col=lane&15, row=(lane>>4)*4+reg
    int lr = lane >> 4, lc = lane & 15;
    #pragma unroll
    for (int mi = 0; mi < 4; ++mi) {
        #pragma unroll
        for (int r = 0; r < 4; ++r) {
            int m_local = wm * 64 + mi * 16 + lr * 4 + r;
            int grow = mtile * BM + m_local;
            if (grow < count) {
                size_t base = (size_t)(off + grow) * IDIM + ntile * BN + wn * 64;
                #pragma unroll
                for (int ni = 0; ni < 4; ++ni) {
                    float v = gelu_exact(acc1[mi][ni][r]) * acc3[mi][ni][r];
                    act[base + ni * 16 + lc] = (bf16)v;
                }
            }
        }
    }
}

// ---------------- GEMM2: pair_out = (act @ w2^T) * route_w -------------------------------
__global__ __launch_bounds__(256, 2) void gemm2_kernel(
    const bf16* __restrict__ act, const float* __restrict__ w2,
    const int* __restrict__ ctrl, const float* __restrict__ pair_w,
    float* __restrict__ pair_out)
{
    int e = blockIdx.z;
    int count = ctrl[e];
    int mtile = blockIdx.y;
    if (mtile * BM >= count) return;
    int off = ctrl[16 + e];
    int ntile = blockIdx.x;   // 0..7 over HDIM

    __shared__ bf16 As[BM][APAD];
    __shared__ bf16 Bs[BM][APAD];

    int tid = threadIdx.x;
    int lane = tid & 63, wave = tid >> 6;
    int wm = wave >> 1, wn = wave & 1;

    int sr = tid >> 1;
    int sc = (tid & 1) * 16;

    const bf16* aptr = act + (size_t)(off + mtile * BM + sr) * IDIM + sc;
    const float* bp = w2 + (size_t)e * HDIM * IDIM + (size_t)(ntile * BN + sr) * IDIM + sc;

    f32x4 acc[4][4] = {};

    for (int k0 = 0; k0 < IDIM; k0 += BK) {
        __syncthreads();
        *(uint4*)&As[sr][sc]     = *(const uint4*)(aptr + k0);
        *(uint4*)&As[sr][sc + 8] = *(const uint4*)(aptr + k0 + 8);
        f32x4 a0 = *(const f32x4*)(bp + k0);
        f32x4 a1 = *(const f32x4*)(bp + k0 + 4);
        f32x4 a2 = *(const f32x4*)(bp + k0 + 8);
        f32x4 a3 = *(const f32x4*)(bp + k0 + 12);
        *(bf16x8*)&Bs[sr][sc]     = cvt8(a0, a1);
        *(bf16x8*)&Bs[sr][sc + 8] = cvt8(a2, a3);
        __syncthreads();

        bf16x8 af[4];
        #pragma unroll
        for (int mi = 0; mi < 4; ++mi)
            af[mi] = *(const bf16x8*)&As[wm * 64 + mi * 16 + (lane & 15)][(lane >> 4) * 8];
        #pragma unroll
        for (int ni = 0; ni < 4; ++ni) {
            bf16x8 bf = *(const bf16x8*)&Bs[wn * 64 + ni * 16 + (lane & 15)][(lane >> 4) * 8];
            #pragma unroll
            for (int mi = 0; mi < 4; ++mi)
                acc[mi][ni] = __builtin_amdgcn_mfma_f32_16x16x32_bf16(af[mi], bf, acc[mi][ni], 0, 0, 0);
        }
    }

    int lr = lane >> 4, lc = lane & 15;
    #pragma unroll
    for (int mi = 0; mi < 4; ++mi) {
        #pragma unroll
        for (int r = 0; r < 4; ++r) {
            int m_local = wm * 64 + mi * 16 + lr * 4 + r;
            int grow = mtile * BM + m_local;
            if (grow < count) {
                float w = pair_w[off + grow];
                size_t base = (size_t)(off + grow) * HDIM + ntile * BN + wn * 64;
                #pragma unroll
                for (int ni = 0; ni < 4; ++ni)
                    pair_out[base + ni * 16 + lc] = acc[mi][ni][r] * w;
            }
        }
    }
}

// ---------------- Combine: out[t] = pair_out[slot0] + pair_out[slot1] --------------------
__global__ __launch_bounds__(256) void combine_kernel(
    const float* __restrict__ pair_out, const int* __restrict__ token_slot,
    float* __restrict__ out)
{
    int t = blockIdx.x;
    int s0 = token_slot[2 * t], s1 = token_slot[2 * t + 1];
    int c = threadIdx.x * 4;
    f32x4 a = *(const f32x4*)(pair_out + (size_t)s0 * HDIM + c);
    f32x4 b = *(const f32x4*)(pair_out + (size_t)s1 * HDIM + c);
    *(f32x4*)(out + (size_t)t * HDIM + c) = a + b;
}

extern "C" void kernel_launch(void* const* d_in, const int* in_sizes, int n_in,
                              void* d_out, int out_size, void* d_ws, size_t ws_size,
                              hipStream_t stream) {
    const float* x  = (const float*)d_in[0];
    const float* wg = (const float*)d_in[1];
    const float* w1 = (const float*)d_in[2];
    const float* w3 = (const float*)d_in[3];
    const float* w2 = (const float*)d_in[4];
    float* out = (float*)d_out;

    char* ws = (char*)d_ws;
    size_t o = 0;
    int*   ctrl       = (int*)(ws + o);   o += 256;
    int*   route_ids  = (int*)(ws + o);   o += 4096 * 4;
    float* route_w    = (float*)(ws + o); o += 4096 * 4;
    int*   token_slot = (int*)(ws + o);   o += 4096 * 4;
    int*   pair_token = (int*)(ws + o);   o += 4352 * 4;
    float* pair_w     = (float*)(ws + o); o += 4352 * 4;
    bf16*  xb         = (bf16*)(ws + o);  o += (size_t)NTOK * HDIM * 2;
    bf16*  act        = (bf16*)(ws + o);  o += (size_t)4224 * IDIM * 2;   // 4096 pairs + 128 pad rows
    float* pair_out   = (float*)(ws + o); o += (size_t)4224 * HDIM * 4;

    hipMemsetAsync(ctrl, 0, 256, stream);
    router_kernel<<<NTOK / 4, 256, 0, stream>>>(x, wg, ctrl, route_ids, route_w, xb);
    offsets_kernel<<<1, 64, 0, stream>>>(ctrl);
    scatter_kernel<<<NTOK / 256, 256, 0, stream>>>(route_ids, route_w, ctrl, pair_token, pair_w, token_slot);
    gemm1_kernel<<<dim3(IDIM / BN, 16, NEXP), 256, 0, stream>>>(xb, w1, w3, ctrl, pair_token, act);
    gemm2_kernel<<<dim3(HDIM / BN, 16, NEXP), 256, 0, stream>>>(act, w2, ctrl, pair_w, pair_out);
    combine_kernel<<<NTOK, 256, 0, stream>>>(pair_out, token_slot, out);
}

// Round 2
// 635.076 us; speedup vs baseline: 1.3334x; 1.3334x over previous
//
#include <hip/hip_runtime.h>
#include <hip/hip_bf16.h>
#include <math.h>

// Grok1 MoE: T=2048, H=1024, I=4096, E=8, top-2, softcap=30. Sparse top-2 path.
// R2: split-K gemm2 (occupancy 10%->~40%), register-prefetch pipelined K-loops,
//     gemm1 BN=64 (acc 128->64 regs, 3 blocks/CU).

#define NTOK 2048
#define HDIM 1024
#define IDIM 4096
#define NEXP 8
#define SOFTCAP 30.0f
#define PAIR_CAP 4224

typedef __bf16 bf16;
typedef __bf16 bf16x8 __attribute__((ext_vector_type(8)));
typedef float f32x4 __attribute__((ext_vector_type(4)));

#define BM 128
#define BK 32
#define APAD 40   // 80B rows: 16B-aligned, breaks pow2 bank stride

__device__ inline float gelu_exact(float x) {
    return 0.5f * x * (1.0f + erff(x * 0.70710678118654752f));
}

__device__ inline bf16x8 cvt8(f32x4 a, f32x4 b) {
    bf16x8 r;
    r[0] = (bf16)a[0]; r[1] = (bf16)a[1]; r[2] = (bf16)a[2]; r[3] = (bf16)a[3];
    r[4] = (bf16)b[0]; r[5] = (bf16)b[1]; r[6] = (bf16)b[2]; r[7] = (bf16)b[3];
    return r;
}

// ---------------- Router ---------------------------------------------------------------
__global__ __launch_bounds__(256) void router_kernel(
    const float* __restrict__ x, const float* __restrict__ wg,
    int* __restrict__ ctrl, int* __restrict__ route_ids, float* __restrict__ route_w,
    bf16* __restrict__ xb)
{
    int wave = threadIdx.x >> 6;
    int lane = threadIdx.x & 63;
    int t = blockIdx.x * 4 + wave;
    if (t >= NTOK) return;

    const float* xr = x + (size_t)t * HDIM;
    float xv[16];
    #pragma unroll
    for (int j = 0; j < 16; ++j) xv[j] = xr[lane + 64 * j];
    #pragma unroll
    for (int j = 0; j < 16; ++j) xb[(size_t)t * HDIM + lane + 64 * j] = (bf16)xv[j];

    float l[NEXP];
    #pragma unroll
    for (int e = 0; e < NEXP; ++e) {
        const float* wr = wg + e * HDIM;
        float p = 0.f;
        #pragma unroll
        for (int j = 0; j < 16; ++j) p += xv[j] * wr[lane + 64 * j];
        #pragma unroll
        for (int off = 32; off > 0; off >>= 1) p += __shfl_xor(p, off);
        l[e] = SOFTCAP * tanhf(p * (1.0f / SOFTCAP));
    }
    int e0 = 0; float v0 = l[0];
    #pragma unroll
    for (int e = 1; e < NEXP; ++e) if (l[e] > v0) { v0 = l[e]; e0 = e; }
    int e1 = (e0 == 0) ? 1 : 0; float v1 = l[e1];
    #pragma unroll
    for (int e = 0; e < NEXP; ++e) if (e != e0 && l[e] > v1) { v1 = l[e]; e1 = e; }
    float w0 = 1.0f / (1.0f + expf(v1 - v0));   // top-2 softmax renorm == pairwise sigmoid

    if (lane == 0) {
        route_ids[2 * t] = e0; route_ids[2 * t + 1] = e1;
        route_w[2 * t] = w0;   route_w[2 * t + 1] = 1.0f - w0;
        atomicAdd(&ctrl[e0], 1);
        atomicAdd(&ctrl[e1], 1);
    }
}

// ctrl: [0..7]=counts, [8..15]=cursor, [16..24]=offsets
__global__ void offsets_kernel(int* __restrict__ ctrl) {
    if (threadIdx.x == 0) {
        int acc = 0;
        for (int e = 0; e < NEXP; ++e) { ctrl[16 + e] = acc; acc += ctrl[e]; ctrl[8 + e] = 0; }
        ctrl[16 + NEXP] = acc;
    }
}

__global__ __launch_bounds__(256) void scatter_kernel(
    const int* __restrict__ route_ids, const float* __restrict__ route_w,
    int* __restrict__ ctrl, int* __restrict__ pair_token, float* __restrict__ pair_w,
    int* __restrict__ token_slot)
{
    int t = blockIdx.x * 256 + threadIdx.x;
    if (t >= NTOK) return;
    #pragma unroll
    for (int k = 0; k < 2; ++k) {
        int e = route_ids[2 * t + k];
        int slot = atomicAdd(&ctrl[8 + e], 1);
        int pos = ctrl[16 + e] + slot;
        pair_token[pos] = t;
        pair_w[pos] = route_w[2 * t + k];
        token_slot[2 * t + k] = pos;
    }
}

// ---------------- GEMM1: act = gelu(Xg@w1^T) * (Xg@w3^T), BM=128 x BN=64 ---------------
__global__ __launch_bounds__(256, 3) void gemm1_kernel(
    const bf16* __restrict__ xb, const float* __restrict__ w1, const float* __restrict__ w3,
    const int* __restrict__ ctrl, const int* __restrict__ pair_token,
    bf16* __restrict__ act)
{
    int e = blockIdx.z;
    int count = ctrl[e];
    int mtile = blockIdx.y;
    if (mtile * BM >= count) return;
    int off = ctrl[16 + e];
    int ntile = blockIdx.x;            // 0..63 over IDIM/64

    __shared__ bf16 As[BM][APAD];
    __shared__ bf16 B1s[64][APAD];
    __shared__ bf16 B3s[64][APAD];

    int tid = threadIdx.x;
    int lane = tid & 63, wave = tid >> 6;
    int wm = wave >> 1, wn = wave & 1;   // 2x2 waves -> 64x32 per wave

    int ar = tid >> 1, ac = (tid & 1) * 16;       // A staging: 128 rows x 32B
    int br = tid >> 2, bc = (tid & 3) * 8;        // B staging: 64 rows x 32B (8 fp32)

    int arow = mtile * BM + ar;
    int tok = (arow < count) ? pair_token[off + arow] : 0;
    const bf16*  aptr = xb + (size_t)tok * HDIM + ac;
    const float* b1p  = w1 + (size_t)e * IDIM * HDIM + (size_t)(ntile * 64 + br) * HDIM + bc;
    const float* b3p  = w3 + (size_t)e * IDIM * HDIM + (size_t)(ntile * 64 + br) * HDIM + bc;

    f32x4 acc1[4][2] = {};
    f32x4 acc3[4][2] = {};

    uint4 pa0, pa1;
    f32x4 q1[2], q3[2];
    #define G1_LOAD(K0) do { \
        pa0 = *(const uint4*)(aptr + (K0));      pa1 = *(const uint4*)(aptr + (K0) + 8); \
        q1[0] = *(const f32x4*)(b1p + (K0));     q1[1] = *(const f32x4*)(b1p + (K0) + 4); \
        q3[0] = *(const f32x4*)(b3p + (K0));     q3[1] = *(const f32x4*)(b3p + (K0) + 4); \
    } while (0)

    G1_LOAD(0);
    for (int k0 = 0; k0 < HDIM; k0 += BK) {
        __syncthreads();
        *(uint4*)&As[ar][ac]     = pa0;
        *(uint4*)&As[ar][ac + 8] = pa1;
        *(bf16x8*)&B1s[br][bc]   = cvt8(q1[0], q1[1]);
        *(bf16x8*)&B3s[br][bc]   = cvt8(q3[0], q3[1]);
        __syncthreads();
        if (k0 + BK < HDIM) G1_LOAD(k0 + BK);   // overlaps ds_read+MFMA below

        bf16x8 af[4];
        #pragma unroll
        for (int mi = 0; mi < 4; ++mi)
            af[mi] = *(const bf16x8*)&As[wm * 64 + mi * 16 + (lane & 15)][(lane >> 4) * 8];
        #pragma unroll
        for (int ni = 0; ni < 2; ++ni) {
            bf16x8 b1f = *(const bf16x8*)&B1s[wn * 32 + ni * 16 + (lane & 15)][(lane >> 4) * 8];
            bf16x8 b3f = *(const bf16x8*)&B3s[wn * 32 + ni * 16 + (lane & 15)][(lane >> 4) * 8];
            #pragma unroll
            for (int mi = 0; mi < 4; ++mi) {
                acc1[mi][ni] = __builtin_amdgcn_mfma_f32_16x16x32_bf16(af[mi], b1f, acc1[mi][ni], 0, 0, 0);
                acc3[mi][ni] = __builtin_amdgcn_mfma_f32_16x16x32_bf16(af[mi], b3f, acc3[mi][ni], 0, 0, 0);
            }
        }
    }

    int lr = lane >> 4, lc = lane & 15;
    #pragma unroll
    for (int mi = 0; mi < 4; ++mi) {
        #pragma unroll
        for (int r = 0; r < 4; ++r) {
            int m_local = wm * 64 + mi * 16 + lr * 4 + r;
            int grow = mtile * BM + m_local;
            if (grow < count) {
                size_t base = (size_t)(off + grow) * IDIM + ntile * 64 + wn * 32;
                #pragma unroll
                for (int ni = 0; ni < 2; ++ni) {
                    float v = gelu_exact(acc1[mi][ni][r]) * acc3[mi][ni][r];
                    act[base + ni * 16 + lc] = (bf16)v;
                }
            }
        }
    }
}

// ---------------- GEMM2 (split-K): part[ks] = (act @ w2_chunk^T) * w ---------------------
#define BN2 128
__global__ __launch_bounds__(256, 3) void gemm2_kernel(
    const bf16* __restrict__ act, const float* __restrict__ w2,
    const int* __restrict__ ctrl, const float* __restrict__ pair_w,
    float* __restrict__ part, int ksplit)
{
    int z = blockIdx.z;
    int e = z / ksplit;
    int ks = z - e * ksplit;
    int count = ctrl[e];
    int mtile = blockIdx.y;
    if (mtile * BM >= count) return;
    int off = ctrl[16 + e];
    int ntile = blockIdx.x;                 // 0..7 over HDIM/128
    int klen = IDIM / ksplit;
    int kbeg = ks * klen;

    __shared__ bf16 As[BM][APAD];
    __shared__ bf16 Bs[BN2][APAD];

    int tid = threadIdx.x;
    int lane = tid & 63, wave = tid >> 6;
    int wm = wave >> 1, wn = wave & 1;      // 2x2 waves -> 64x64 per wave

    int sr = tid >> 1, sc = (tid & 1) * 16;

    const bf16*  aptr = act + (size_t)(off + mtile * BM + sr) * IDIM + sc;
    const float* bp   = w2 + (size_t)e * HDIM * IDIM + (size_t)(ntile * BN2 + sr) * IDIM + sc;

    f32x4 acc[4][4] = {};

    uint4 pa0, pa1;
    f32x4 q[4];
    #define G2_LOAD(K0) do { \
        pa0 = *(const uint4*)(aptr + (K0));   pa1 = *(const uint4*)(aptr + (K0) + 8); \
        q[0] = *(const f32x4*)(bp + (K0));    q[1] = *(const f32x4*)(bp + (K0) + 4); \
        q[2] = *(const f32x4*)(bp + (K0) + 8); q[3] = *(const f32x4*)(bp + (K0) + 12); \
    } while (0)

    G2_LOAD(kbeg);
    for (int k0 = kbeg; k0 < kbeg + klen; k0 += BK) {
        __syncthreads();
        *(uint4*)&As[sr][sc]     = pa0;
        *(uint4*)&As[sr][sc + 8] = pa1;
        *(bf16x8*)&Bs[sr][sc]     = cvt8(q[0], q[1]);
        *(bf16x8*)&Bs[sr][sc + 8] = cvt8(q[2], q[3]);
        __syncthreads();
        if (k0 + BK < kbeg + klen) G2_LOAD(k0 + BK);

        bf16x8 af[4];
        #pragma unroll
        for (int mi = 0; mi < 4; ++mi)
            af[mi] = *(const bf16x8*)&As[wm * 64 + mi * 16 + (lane & 15)][(lane >> 4) * 8];
        #pragma unroll
        for (int ni = 0; ni < 4; ++ni) {
            bf16x8 bf = *(const bf16x8*)&Bs[wn * 64 + ni * 16 + (lane & 15)][(lane >> 4) * 8];
            #pragma unroll
            for (int mi = 0; mi < 4; ++mi)
                acc[mi][ni] = __builtin_amdgcn_mfma_f32_16x16x32_bf16(af[mi], bf, acc[mi][ni], 0, 0, 0);
        }
    }

    float* outp = part + (size_t)ks * PAIR_CAP * HDIM;
    int lr = lane >> 4, lc = lane & 15;
    #pragma unroll
    for (int mi = 0; mi < 4; ++mi) {
        #pragma unroll
        for (int r = 0; r < 4; ++r) {
            int m_local = wm * 64 + mi * 16 + lr * 4 + r;
            int grow = mtile * BM + m_local;
            if (grow < count) {
                float w = pair_w[off + grow];
                size_t base = (size_t)(off + grow) * HDIM + ntile * BN2 + wn * 64;
                #pragma unroll
                for (int ni = 0; ni < 4; ++ni)
                    outp[base + ni * 16 + lc] = acc[mi][ni][r] * w;
            }
        }
    }
}

// ---------------- Combine: out[t] = sum_ks part[ks][s0] + part[ks][s1] -------------------
__global__ __launch_bounds__(256) void combine_kernel(
    const float* __restrict__ part, const int* __restrict__ token_slot,
    float* __restrict__ out, int ksplit)
{
    int t = blockIdx.x;
    int s0 = token_slot[2 * t], s1 = token_slot[2 * t + 1];
    int c = threadIdx.x * 4;
    f32x4 acc = {0.f, 0.f, 0.f, 0.f};
    for (int ks = 0; ks < ksplit; ++ks) {
        const float* slab = part + (size_t)ks * PAIR_CAP * HDIM;
        acc += *(const f32x4*)(slab + (size_t)s0 * HDIM + c);
        acc += *(const f32x4*)(slab + (size_t)s1 * HDIM + c);
    }
    *(f32x4*)(out + (size_t)t * HDIM + c) = acc;
}

extern "C" void kernel_launch(void* const* d_in, const int* in_sizes, int n_in,
                              void* d_out, int out_size, void* d_ws, size_t ws_size,
                              hipStream_t stream) {
    const float* x  = (const float*)d_in[0];
    const float* wg = (const float*)d_in[1];
    const float* w1 = (const float*)d_in[2];
    const float* w3 = (const float*)d_in[3];
    const float* w2 = (const float*)d_in[4];
    float* out = (float*)d_out;

    char* ws = (char*)d_ws;
    size_t o = 0;
    int*   ctrl       = (int*)(ws + o);   o += 256;
    int*   route_ids  = (int*)(ws + o);   o += 4096 * 4;
    float* route_w    = (float*)(ws + o); o += 4096 * 4;
    int*   token_slot = (int*)(ws + o);   o += 4096 * 4;
    int*   pair_token = (int*)(ws + o);   o += 4352 * 4;
    float* pair_w     = (float*)(ws + o); o += 4352 * 4;
    bf16*  xb         = (bf16*)(ws + o);  o += (size_t)NTOK * HDIM * 2;
    bf16*  act        = (bf16*)(ws + o);  o += (size_t)PAIR_CAP * IDIM * 2;
    float* part       = (float*)(ws + o);                 // ksplit slabs follow

    size_t slab = (size_t)PAIR_CAP * HDIM * 4;
    int ksplit = 4;                                        // choose by available ws (constant per session)
    if (o + 4 * slab > ws_size) ksplit = 2;
    if (o + 2 * slab > ws_size) ksplit = 1;

    hipMemsetAsync(ctrl, 0, 256, stream);
    router_kernel<<<NTOK / 4, 256, 0, stream>>>(x, wg, ctrl, route_ids, route_w, xb);
    offsets_kernel<<<1, 64, 0, stream>>>(ctrl);
    scatter_kernel<<<NTOK / 256, 256, 0, stream>>>(route_ids, route_w, ctrl, pair_token, pair_w, token_slot);
    gemm1_kernel<<<dim3(IDIM / 64, 32, NEXP), 256, 0, stream>>>(xb, w1, w3, ctrl, pair_token, act);
    gemm2_kernel<<<dim3(HDIM / BN2, 32, NEXP * ksplit), 256, 0, stream>>>(act, w2, ctrl, pair_w, part, ksplit);
    combine_kernel<<<NTOK, 256, 0, stream>>>(part, token_slot, out, ksplit);
}